// Round 2
// baseline (2290.690 us; speedup 1.0000x reference)
//
#include <hip/hip_runtime.h>
#include <hip/hip_bf16.h>

typedef float f32x4 __attribute__((ext_vector_type(4)));
typedef unsigned short u16;
typedef unsigned short u16x4 __attribute__((ext_vector_type(4)));
typedef unsigned short u16x8 __attribute__((ext_vector_type(8)));

#define NEG_MAX (-3.4028234663852886e38f)
#define NODE_SCALE 0.125f
#define EDGE_SCALE 0.70710678118654752f

__device__ __forceinline__ float bf2f(u16 u) {
  unsigned int w = ((unsigned int)u) << 16;
  return __builtin_bit_cast(float, w);
}
__device__ __forceinline__ u16 f2bf(float f) {
  unsigned int x = __builtin_bit_cast(unsigned int, f);
  x = x + 0x7FFFu + ((x >> 16) & 1u);
  return (u16)(x >> 16);
}

// direct global -> LDS, 16B per lane. LDS dest must be wave-uniform base;
// lane l writes lds + l*16.
__device__ __forceinline__ void gl_lds16(const float* g, float* l) {
  __builtin_amdgcn_global_load_lds(
      (__attribute__((address_space(1))) void*)g,
      (__attribute__((address_space(3))) void*)l, 16, 0, 0);
}

// ---------------- kernel M: normalize mask to float 0/1 (dtype-robust) ----
__global__ void mask_norm(const unsigned char* __restrict__ mraw,
                          float* __restrict__ mask_f) {
  __shared__ int flags;
  int t = threadIdx.x;
  if (t == 0) flags = 0;
  __syncthreads();
  const unsigned int* mu = (const unsigned int*)mraw;
  int f = 0;
  for (int e = t; e < 512; e += 256) { if (mu[e] > 1u) f |= 1; }
  for (int e = t; e < 2048; e += 256) { if (mraw[e] > 1) f |= 2; }
  if (f) atomicOr(&flags, f);
  __syncthreads();
  int fl = flags;
  for (int e = t; e < 2048; e += 256) {
    float v;
    if (!(fl & 1))      v = (mu[e] != 0u) ? 1.f : 0.f;
    else if (!(fl & 2)) v = (mraw[e] != 0) ? 1.f : 0.f;
    else                v = (((const float*)mraw)[e] != 0.f) ? 1.f : 0.f;
    mask_f[e] = v;
  }
}

// ---------------- kernel A: qkv projection + rotary ----------------------
__global__ __launch_bounds__(256) void qkv_rope(
    const float* __restrict__ node, const float* __restrict__ Wq,
    const float* __restrict__ Wk, const float* __restrict__ Wv,
    float* __restrict__ qw, u16* __restrict__ kwb, u16* __restrict__ vwb) {
  __shared__ __align__(16) float xs[8 * 256];
  int t = threadIdx.x;
  int row0 = blockIdx.x * 8;
#pragma unroll
  for (int p = 0; p < 2; ++p) {
    int f = p * 256 + t;
    *(f32x4*)(&xs[f * 4]) = *(const f32x4*)(node + (size_t)row0 * 256 + f * 4);
  }
  __syncthreads();
  float qa[8], ka[8], va[8];
#pragma unroll
  for (int r = 0; r < 8; ++r) { qa[r] = 0.f; ka[r] = 0.f; va[r] = 0.f; }
  for (int c = 0; c < 256; ++c) {
    float wq = Wq[c * 256 + t];
    float wk = Wk[c * 256 + t];
    float wv = Wv[c * 256 + t];
#pragma unroll
    for (int r = 0; r < 8; ++r) {
      float x = xs[r * 256 + c];
      qa[r] += x * wq; ka[r] += x * wk; va[r] += x * wv;
    }
  }
  int d = t & 31;
  float inv = powf(10000.f, -((float)(2 * (d >> 1)) * (1.f / 32.f)));
  int h = t >> 5;
#pragma unroll
  for (int r = 0; r < 8; ++r) {
    int gr = row0 + r;
    int b = gr >> 10, i = gr & 1023;
    float ang = (float)i * inv;
    float sn, cs;
    sincosf(ang, &sn, &cs);
    float qp = __shfl_xor(qa[r], 1, 64);
    float kp = __shfl_xor(ka[r], 1, 64);
    float qo = (d & 1) ? (qp * sn + qa[r] * cs) : (qa[r] * cs - qp * sn);
    float ko = (d & 1) ? (kp * sn + ka[r] * cs) : (ka[r] * cs - kp * sn);
    int idx = ((b * 8 + h) * 1024 + i) * 32 + d;
    qw[idx] = qo;
    kwb[idx] = f2bf(ko);
    vwb[idx] = f2bf(va[r]);
  }
}

// ---------------- kernel B: fused attention (single pass over edge) ------
__global__ __launch_bounds__(256, 3) void attn_fused(
    const float* __restrict__ edge, const float* __restrict__ qw,
    const u16* __restrict__ kwb, const u16* __restrict__ vwb,
    const float* __restrict__ We, const float* __restrict__ be,
    const float* __restrict__ mask_f, float* __restrict__ rescat) {
  __shared__ __align__(16) float buf[2][4096];  // double-buffered 64x64 f32 tile
  __shared__ __align__(16) float Lg[8][64];     // p values per head
  __shared__ __align__(16) float WesT[8][64];   // We transposed [h][d]
  __shared__ __align__(16) float qs[256];       // q[h][d] for this i
  __shared__ float bes[8], mS[8], sS[8], rS[8];

  int bid = blockIdx.x;
  int xcd = bid & 7, slot = bid >> 3;
  int b = xcd >> 2;
  int i = (xcd & 3) * 256 + slot;
  int t = threadIdx.x;
  int lane = t & 63;
  int wave = __builtin_amdgcn_readfirstlane(t >> 6);

  {
    int h = t >> 5, d = t & 31;
    qs[t] = qw[((b * 8 + h) * 1024 + i) * 32 + d];
  }
#pragma unroll
  for (int p = 0; p < 2; ++p) { int e = p * 256 + t; WesT[e & 7][e >> 3] = We[e]; }
  if (t < 8) { bes[t] = be[t]; mS[t] = NEG_MAX; sS[t] = 0.f; rS[t] = 1.f; }

  float mi = mask_f[b * 1024 + i];
  const float* ebase = edge + ((size_t)(b * 1024 + i)) * (1024 * 64);

  // prologue: tile 0 -> buf[0]
#pragma unroll
  for (int ii = 0; ii < 4; ++ii) {
    int C = (wave * 4 + ii) * 256;
    gl_lds16(ebase + C + lane * 4, &buf[0][C]);
  }

  f32x4 acc_v = {0.f, 0.f, 0.f, 0.f};
  f32x4 acce[8];
#pragma unroll
  for (int h = 0; h < 8; ++h) acce[h] = (f32x4){0.f, 0.f, 0.f, 0.f};

  int h3a = t >> 5, dq3a = (t >> 2) & 7, rep3a = t & 3;  // phase 3a map
  int dq = t & 15, jg = t >> 4;                           // phase 3b map
  int h1 = wave, h2 = wave + 4;
  int sw = lane & 7;

  asm volatile("s_waitcnt vmcnt(0) lgkmcnt(0)" ::: "memory");
  __builtin_amdgcn_s_barrier();

  int cur = 0;
  for (int j0 = 0; j0 < 1024; j0 += 64) {
    // ---- prefetch tile t+1 into buf[cur^1] (stays in flight past barrier 1)
    if (j0 + 64 < 1024) {
      const float* eb = ebase + (size_t)(j0 + 64) * 64;
#pragma unroll
      for (int ii = 0; ii < 4; ++ii) {
        int C = (wave * 4 + ii) * 256;
        gl_lds16(eb + C + lane * 4, &buf[cur ^ 1][C]);
      }
    }
    const float* bufc = &buf[cur][0];

    // ---- phase 1+2: logits + online softmax (head h1=wave, h2=wave+4) ---
    {
      int j = lane;
      float bias1 = 0.f, bias2 = 0.f;
#pragma unroll
      for (int k = 0; k < 16; ++k) {
        int s = (k & 8) | ((k & 7) ^ sw);  // bank-staggered column order
        f32x4 ev = *(const f32x4*)(bufc + j * 64 + s * 4);
        f32x4 wa = *(const f32x4*)(&WesT[h1][s * 4]);
        f32x4 wb = *(const f32x4*)(&WesT[h2][s * 4]);
        bias1 += ev.x * wa.x + ev.y * wa.y + ev.z * wa.z + ev.w * wa.w;
        bias2 += ev.x * wb.x + ev.y * wb.y + ev.z * wb.z + ev.w * wb.w;
      }
      float qk1 = 0.f, qk2 = 0.f;
      const u16* kr1 = kwb + ((size_t)((b * 8 + h1) * 1024 + j0 + j)) * 32;
      const u16* kr2 = kwb + ((size_t)((b * 8 + h2) * 1024 + j0 + j)) * 32;
#pragma unroll
      for (int g = 0; g < 4; ++g) {
        u16x8 k1 = *(const u16x8*)(kr1 + g * 8);
        u16x8 k2 = *(const u16x8*)(kr2 + g * 8);
        f32x4 q1a = *(const f32x4*)(&qs[h1 * 32 + g * 8]);
        f32x4 q1b = *(const f32x4*)(&qs[h1 * 32 + g * 8 + 4]);
        f32x4 q2a = *(const f32x4*)(&qs[h2 * 32 + g * 8]);
        f32x4 q2b = *(const f32x4*)(&qs[h2 * 32 + g * 8 + 4]);
        qk1 += bf2f(k1[0]) * q1a.x + bf2f(k1[1]) * q1a.y + bf2f(k1[2]) * q1a.z + bf2f(k1[3]) * q1a.w
             + bf2f(k1[4]) * q1b.x + bf2f(k1[5]) * q1b.y + bf2f(k1[6]) * q1b.z + bf2f(k1[7]) * q1b.w;
        qk2 += bf2f(k2[0]) * q2a.x + bf2f(k2[1]) * q2a.y + bf2f(k2[2]) * q2a.z + bf2f(k2[3]) * q2a.w
             + bf2f(k2[4]) * q2b.x + bf2f(k2[5]) * q2b.y + bf2f(k2[6]) * q2b.z + bf2f(k2[7]) * q2b.w;
      }
      bool pm = (mi != 0.f) && (mask_f[b * 1024 + j0 + j] != 0.f);
      float l1 = pm ? (NODE_SCALE * qk1 + EDGE_SCALE * (bias1 + bes[h1])) : NEG_MAX;
      float l2 = pm ? (NODE_SCALE * qk2 + EDGE_SCALE * (bias2 + bes[h2])) : NEG_MAX;
      float mx1 = l1, mx2 = l2;
#pragma unroll
      for (int off = 32; off; off >>= 1) {
        mx1 = fmaxf(mx1, __shfl_xor(mx1, off, 64));
        mx2 = fmaxf(mx2, __shfl_xor(mx2, off, 64));
      }
      float mo1 = mS[h1], mo2 = mS[h2];
      float mn1 = fmaxf(mo1, mx1), mn2 = fmaxf(mo2, mx2);
      float p1 = __expf(l1 - mn1), p2 = __expf(l2 - mn2);
      float ps1 = p1, ps2 = p2;
#pragma unroll
      for (int off = 32; off; off >>= 1) {
        ps1 += __shfl_xor(ps1, off, 64);
        ps2 += __shfl_xor(ps2, off, 64);
      }
      Lg[h1][j] = p1;
      Lg[h2][j] = p2;
      if (lane == 0) {
        float r1 = __expf(mo1 - mn1), r2 = __expf(mo2 - mn2);
        rS[h1] = r1; sS[h1] = sS[h1] * r1 + ps1; mS[h1] = mn1;
        rS[h2] = r2; sS[h2] = sS[h2] * r2 + ps2; mS[h2] = mn2;
      }
    }
    // barrier 1: only LDS ordering needed; prefetch stays in flight (no vmcnt)
    asm volatile("s_waitcnt lgkmcnt(0)" ::: "memory");
    __builtin_amdgcn_s_barrier();

    // ---- phase 3a: acc_v (thread: h3a, d-quad dq3a, j-chunk rep3a) ------
    {
      float r = rS[h3a];
      const u16* vb = vwb + ((size_t)((b * 8 + h3a) * 1024 + j0 + rep3a * 16)) * 32 + dq3a * 4;
      f32x4 s4 = {0.f, 0.f, 0.f, 0.f};
#pragma unroll
      for (int x = 0; x < 16; ++x) {
        float p = Lg[h3a][rep3a * 16 + x];
        u16x4 vv = *(const u16x4*)(vb + (size_t)x * 32);
        s4.x += p * bf2f(vv[0]);
        s4.y += p * bf2f(vv[1]);
        s4.z += p * bf2f(vv[2]);
        s4.w += p * bf2f(vv[3]);
      }
      acc_v = acc_v * r + s4;
    }
    // ---- phase 3b: acc_e (thread: d-quad dq, j-group jg of 4 rows) ------
    {
      int jb = jg * 4;
      f32x4 ev0 = *(const f32x4*)(bufc + (jb + 0) * 64 + dq * 4);
      f32x4 ev1 = *(const f32x4*)(bufc + (jb + 1) * 64 + dq * 4);
      f32x4 ev2 = *(const f32x4*)(bufc + (jb + 2) * 64 + dq * 4);
      f32x4 ev3 = *(const f32x4*)(bufc + (jb + 3) * 64 + dq * 4);
#pragma unroll
      for (int h = 0; h < 8; ++h) {
        f32x4 pv = *(const f32x4*)(&Lg[h][jb]);
        f32x4 a = acce[h] * rS[h];
        a += ev0 * pv.x;
        a += ev1 * pv.y;
        a += ev2 * pv.z;
        a += ev3 * pv.w;
        acce[h] = a;
      }
    }
    // barrier 2: drain everything (prefetch must be in LDS before next read)
    asm volatile("s_waitcnt vmcnt(0) lgkmcnt(0)" ::: "memory");
    __builtin_amdgcn_s_barrier();
    cur ^= 1;
  }

  // ---- epilogue ----------------------------------------------------------
  float* red = &buf[0][0];  // 32 KB scratch
  *(f32x4*)(red + t * 4) = acc_v;
  __syncthreads();
  {
    int h = t >> 5, d = t & 31, dqq = d >> 2, c = d & 3;
    float sum = 0.f;
#pragma unroll
    for (int rp = 0; rp < 4; ++rp)
      sum += red[(((h << 5) | (dqq << 2) | rp) << 2) + c];
    rescat[((size_t)(b * 1024 + i)) * 768 + h * 32 + d] = sum / sS[h];
  }
  __syncthreads();
#pragma unroll
  for (int h = 0; h < 8; ++h)
    *(f32x4*)(red + h * 1024 + jg * 64 + dq * 4) = acce[h];
  __syncthreads();
  {
    int h = t >> 5, d = t & 31;
    float inv = 1.f / sS[h];
    size_t base = ((size_t)(b * 1024 + i)) * 768 + 256;
#pragma unroll
    for (int half = 0; half < 2; ++half) {
      int dd = d + half * 32;
      float sum = 0.f;
#pragma unroll
      for (int g = 0; g < 16; ++g) sum += red[h * 1024 + g * 64 + dd];
      rescat[base + h * 64 + dd] = sum * inv;
    }
  }
}

// ---------------- kernel C: output projection ----------------------------
__global__ __launch_bounds__(256) void out_proj(
    const float* __restrict__ rescat, const float* __restrict__ Wo,
    const float* __restrict__ bo, float* __restrict__ out) {
  __shared__ __align__(16) float xs[8 * 768];
  int t = threadIdx.x;
  int row0 = blockIdx.x * 8;
#pragma unroll
  for (int p = 0; p < 6; ++p) {
    int f = p * 256 + t;
    *(f32x4*)(&xs[f * 4]) = *(const f32x4*)(rescat + (size_t)row0 * 768 + f * 4);
  }
  __syncthreads();
  float acc[8];
#pragma unroll
  for (int r = 0; r < 8; ++r) acc[r] = 0.f;
  for (int c = 0; c < 768; ++c) {
    float w = Wo[c * 256 + t];
#pragma unroll
    for (int r = 0; r < 8; ++r) acc[r] += xs[r * 768 + c] * w;
  }
  float bias = bo[t];
#pragma unroll
  for (int r = 0; r < 8; ++r)
    out[(size_t)(row0 + r) * 256 + t] = acc[r] + bias;
}

// ---------------- launch ---------------------------------------------------
extern "C" void kernel_launch(void* const* d_in, const int* in_sizes, int n_in,
                              void* d_out, int out_size, void* d_ws, size_t ws_size,
                              hipStream_t stream) {
  const float* node = (const float*)d_in[0];
  const float* edge = (const float*)d_in[1];
  const unsigned char* mask = (const unsigned char*)d_in[2];
  const float* Wq = (const float*)d_in[3];
  const float* Wk = (const float*)d_in[4];
  const float* Wv = (const float*)d_in[5];
  const float* We = (const float*)d_in[6];
  const float* be = (const float*)d_in[7];
  const float* Wo = (const float*)d_in[8];
  const float* bo = (const float*)d_in[9];

  float* ws = (float*)d_ws;
  float* qw = ws;                              // 524288 f32
  u16* kwb = (u16*)(ws + 524288);              // 524288 bf16
  u16* vwb = kwb + 524288;                     // 524288 bf16
  float* rescat = ws + 1048576;                // 1572864 f32
  float* mask_f = ws + 2621440;                // 2048 f32

  hipLaunchKernelGGL(mask_norm, dim3(1), dim3(256), 0, stream, mask, mask_f);
  hipLaunchKernelGGL(qkv_rope, dim3(256), dim3(256), 0, stream,
                     node, Wq, Wk, Wv, qw, kwb, vwb);
  hipLaunchKernelGGL(attn_fused, dim3(2048), dim3(256), 0, stream,
                     edge, qw, kwb, vwb, We, be, mask_f, rescat);
  hipLaunchKernelGGL(out_proj, dim3(256), dim3(256), 0, stream,
                     rescat, Wo, bo, (float*)d_out);
}